// Round 7
// baseline (312.635 us; speedup 1.0000x reference)
//
#include <hip/hip_runtime.h>
#include <hip/hip_bf16.h>

// TransitionGNN fused pipeline, r7.
// r7 changes vs r6:
//  (1) agg GEMM eliminated: agg enters n1 linearly -> precompute
//      W_c = eW3 @ nW1_agg (Bt2) + b_fold = nb1 + 15*eb3@nW1_agg;
//      n1 pass-2 reads S directly against Bt2.
//  (2) out-GEMM fused into gemm_ln_out: n2 tile kept in LDS (overlay of the
//      dead B-stage buffer), second MFMA loop vs frag-layout nW3 -> d_out.
//  (3) edge kernel software-pipelined: B-frags register-prefetched 1 kt ahead
//      (barrier drains them "for free"), PQ loads staged at iter top,
//      convert+ds_write after the MFMAs.

using bf16 = __hip_bfloat16;
typedef __attribute__((ext_vector_type(8))) short bf16x8;
typedef __attribute__((ext_vector_type(4))) short short4v;
typedef __attribute__((ext_vector_type(4))) float f32x4;

#define LDK 40  // LDS row stride in bf16 elems (32 + 8 pad)
#define LDN 520 // n2-tile LDS row stride (512 + 8 pad)

__device__ __forceinline__ short f2bf(float f) {
  bf16 h = __float2bfloat16(f);
  return *reinterpret_cast<short*>(&h);
}
__device__ __forceinline__ float bs2f(short s) {
  bf16 h = *reinterpret_cast<bf16*>(&s);
  return __bfloat162float(h);
}

// ---------------------------------------------------------------- convert
__global__ __launch_bounds__(256) void cvt_f32_bf16(
    const float* __restrict__ src, short* __restrict__ dst, int n) {
  int i = (blockIdx.x * 256 + threadIdx.x) * 4;
  if (i >= n) return;
  float4 v = *(const float4*)(src + i);
  short4v o;
  o.x = f2bf(v.x); o.y = f2bf(v.y); o.z = f2bf(v.z); o.w = f2bf(v.w);
  *(short4v*)(dst + i) = o;
}

// ---------------------------------------------------------------- multi-transpose
struct TJob { const float* src; unsigned short* dst; int lds, ldd, R, C; };
struct TJobs { TJob j[5]; };
__global__ __launch_bounds__(256) void transpose_multi(TJobs js) {
  TJob jb = js.j[blockIdx.z];
  int bc = blockIdx.x * 32, br = blockIdx.y * 32;
  if (bc >= jb.C || br >= jb.R) return;
  __shared__ unsigned short tile[32][33];
  int tx = threadIdx.x & 31, ty = threadIdx.x >> 5;
  for (int i = ty; i < 32; i += 8) {
    int r = br + i, c = bc + tx;
    unsigned short u = 0;
    if (r < jb.R && c < jb.C) {
      short s = f2bf(jb.src[(size_t)r * jb.lds + c]);
      u = *reinterpret_cast<unsigned short*>(&s);
    }
    tile[i][tx] = u;
  }
  __syncthreads();
  for (int i = ty; i < 32; i += 8) {
    int c = bc + i, r = br + tx;
    if (c < jb.C && r < jb.R) jb.dst[(size_t)c * jb.ldd + r] = tile[tx][i];
  }
}

// ---------------------------------------------------------------- frag prep
// out[((kt*ncolg + g)*64 + lane)*8 + j] = bf16(W[(kt*32+q*8+j)*ldw + g*16+lc])
// ncolg = cols/16 (power of 2, pass shift).
__global__ __launch_bounds__(256) void prep_wfrag(
    const float* __restrict__ W, short* __restrict__ out, int ncolg_sh,
    int ldw) {
  int o = blockIdx.x * 256 + threadIdx.x;
  int j = o & 7, lane = (o >> 3) & 63, blk = o >> 9;
  int kt = blk >> ncolg_sh, gg = blk & ((1 << ncolg_sh) - 1);
  int q = lane >> 4, lc = lane & 15;
  out[o] = f2bf(W[(size_t)(kt * 32 + q * 8 + j) * ldw + gg * 16 + lc]);
}

// ---------------------------------------------------------------- fold bias
// b_fold[n] = nb1[n] + 15 * sum_h eb3[h]*nW1[(132+h)*512 + n]
__global__ __launch_bounds__(512) void fold_bias(
    const float* __restrict__ nb1, const float* __restrict__ eb3,
    const float* __restrict__ nW1, float* __restrict__ out) {
  int n = threadIdx.x;
  float s = 0.f;
#pragma unroll 8
  for (int h = 0; h < 512; ++h) s += eb3[h] * nW1[(size_t)(132 + h) * 512 + n];
  out[n] = nb1[n] + 15.f * s;
}

// ---------------------------------------------------------------- gemm_bt
template <bool OUT_F32, bool RELU, bool DUAL, bool ACT>
__global__ __launch_bounds__(256) void gemm_bt(
    const bf16* __restrict__ A1, int K1, int lda1,
    const bf16* __restrict__ Bt1, int ldb1,
    const bf16* __restrict__ A2, int K2, int lda2,
    const bf16* __restrict__ Bt2, int ldb2,
    const float* __restrict__ bias, float bscale, int bias_n,
    const int* __restrict__ action, const float* __restrict__ actW,
    void* __restrict__ Cout, int ldc) {
  __shared__ short Alds[128 * LDK];
  __shared__ short Blds[128 * LDK];
  const int t = threadIdx.x;
  const int wid = t >> 6, lane = t & 63, q = lane >> 4, lc = lane & 15;
  const int wm = wid >> 1, wn = wid & 1;
  const int m0 = blockIdx.y * 128, n0 = blockIdx.x * 128;
  const f32x4 zz = {0.f, 0.f, 0.f, 0.f};
  f32x4 acc[4][4];
#pragma unroll
  for (int mb = 0; mb < 4; ++mb)
#pragma unroll
    for (int nb = 0; nb < 4; ++nb) acc[mb][nb] = zz;

  const int sr = t >> 2, seg = t & 3;
#pragma unroll 1
  for (int pass = 0; pass < (DUAL ? 2 : 1); ++pass) {
    const bf16* Ap = pass ? A2 : A1;
    const bf16* Bp = pass ? Bt2 : Bt1;
    const int K = pass ? K2 : K1;
    const int lda = pass ? lda2 : lda1;
    const int ldb = pass ? ldb2 : ldb1;
    for (int k0 = 0; k0 < K; k0 += 32) {
#pragma unroll
      for (int i = 0; i < 2; ++i) {
        int r = i * 64 + sr;
        uint4 va = *(const uint4*)(Ap + (size_t)(m0 + r) * lda + k0 + seg * 8);
        *(uint4*)&Alds[r * LDK + seg * 8] = va;
        uint4 vb = *(const uint4*)(Bp + (size_t)(n0 + r) * ldb + k0 + seg * 8);
        *(uint4*)&Blds[r * LDK + seg * 8] = vb;
      }
      __syncthreads();
      bf16x8 af[4], bfr[4];
#pragma unroll
      for (int mb = 0; mb < 4; ++mb)
        af[mb] = *(const bf16x8*)&Alds[(wm * 64 + mb * 16 + lc) * LDK + q * 8];
#pragma unroll
      for (int nb = 0; nb < 4; ++nb)
        bfr[nb] = *(const bf16x8*)&Blds[(wn * 64 + nb * 16 + lc) * LDK + q * 8];
#pragma unroll
      for (int mb = 0; mb < 4; ++mb)
#pragma unroll
        for (int nb = 0; nb < 4; ++nb)
          acc[mb][nb] = __builtin_amdgcn_mfma_f32_16x16x32_bf16(
              af[mb], bfr[nb], acc[mb][nb], 0, 0, 0);
      __syncthreads();
    }
  }
  float bv[4];
#pragma unroll
  for (int nb = 0; nb < 4; ++nb) {
    int col = n0 + wn * 64 + nb * 16 + lc;
    bv[nb] = (bias && col < bias_n) ? bscale * bias[col] : 0.f;
  }
#pragma unroll
  for (int mb = 0; mb < 4; ++mb) {
    const int rowbase = m0 + wm * 64 + mb * 16;
    int aw = -1, ac4 = 0;
    if (ACT) {
      int a = action[rowbase >> 4];
      aw = a >> 2;
      ac4 = a & 3;
    }
#pragma unroll
    for (int nb = 0; nb < 4; ++nb) {
      int col = n0 + wn * 64 + nb * 16 + lc;
#pragma unroll
      for (int r = 0; r < 4; ++r) {
        float x = acc[mb][nb][r] + bv[nb];
        if (ACT && (q * 4 + r) == aw) x += actW[ac4 * 512 + col];
        if (RELU) x = fmaxf(x, 0.f);
        size_t idx = (size_t)(rowbase + q * 4 + r) * ldc + col;
        if (OUT_F32)
          ((float*)Cout)[idx] = x;
        else
          ((bf16*)Cout)[idx] = __float2bfloat16(x);
      }
    }
  }
}

// ---------------------------------------------------------------- edge kernel v4
// r6 structure + software pipeline: B-frags register-prefetched 1 kt ahead,
// PQ loads staged at iteration top, convert+ds_write after the MFMAs.
__global__ __launch_bounds__(512, 4) void edge_ln_seg4(
    const bf16* __restrict__ PQ, const bf16* __restrict__ Wf,
    const float* __restrict__ b2, const float* __restrict__ g,
    const float* __restrict__ be, bf16* __restrict__ S) {
  __shared__ short Alds[2][64 * LDK];
  __shared__ float s_sum[64 * 8];
  __shared__ float s_sq[64 * 8];
  const int t = threadIdx.x;
  const int w = t >> 6, lane = t & 63, q = lane >> 4, lc = lane & 15;
  const int g0 = blockIdx.x * 4;
  const int bb = g0 >> 4;
  const f32x4 zz = {0.f, 0.f, 0.f, 0.f};
  f32x4 acc[4][4];
#pragma unroll
  for (int mb = 0; mb < 4; ++mb)
#pragma unroll
    for (int nb = 0; nb < 4; ++nb) acc[mb][nb] = zz;

  // A-build mapping: thread t -> row ar (0..63), 4 k's at kk
  const int ar = t >> 3;
  const int kk = (t & 7) * 4;
  const int gA = ar >> 4;
  const int slot = ar & 15;
  const int aiA = (g0 & 15) + gA;
  const bool padA = (slot == 15);
  const int dstA = padA ? 0 : slot + (slot >= aiA ? 1 : 0);
  const bf16* pA = PQ + (size_t)(g0 + gA) * 1024 + kk;
  const bf16* qA = PQ + (size_t)(bb * 16 + dstA) * 1024 + 512 + kk;

  auto cvtwr = [&](short4v pv, short4v qv, int buf) {
    short4v av = {0, 0, 0, 0};
    if (!padA) {
      av.x = f2bf(fmaxf(bs2f(pv.x) + bs2f(qv.x), 0.f));
      av.y = f2bf(fmaxf(bs2f(pv.y) + bs2f(qv.y), 0.f));
      av.z = f2bf(fmaxf(bs2f(pv.z) + bs2f(qv.z), 0.f));
      av.w = f2bf(fmaxf(bs2f(pv.w) + bs2f(qv.w), 0.f));
    }
    *(short4v*)&Alds[buf][ar * LDK + kk] = av;
  };

  // prime: B(0) into regs, A(0) into LDS buf 0
  bf16x8 bnext[4];
#pragma unroll
  for (int nb = 0; nb < 4; ++nb)
    bnext[nb] = *(const bf16x8*)(Wf + (((size_t)0 + w * 4 + nb) * 64 + lane) * 8);
  {
    short4v pv = {0, 0, 0, 0}, qv = {0, 0, 0, 0};
    if (!padA) { pv = *(const short4v*)pA; qv = *(const short4v*)qA; }
    cvtwr(pv, qv, 0);
  }

#pragma unroll 1
  for (int kt = 0; kt < 16; ++kt) {
    __syncthreads();  // A(kt) ready in buf[kt&1]; B(kt) already in bnext
    const int cur = kt & 1;
    // stage PQ(kt+1)
    short4v pv = {0, 0, 0, 0}, qv = {0, 0, 0, 0};
    if (kt < 15 && !padA) {
      pv = *(const short4v*)(pA + (kt + 1) * 32);
      qv = *(const short4v*)(qA + (kt + 1) * 32);
    }
    bf16x8 bfr[4];
#pragma unroll
    for (int nb = 0; nb < 4; ++nb) bfr[nb] = bnext[nb];
    if (kt < 15) {
#pragma unroll
      for (int nb = 0; nb < 4; ++nb)
        bnext[nb] = *(const bf16x8*)(Wf +
                                     (((size_t)(kt + 1) * 32 + w * 4 + nb) * 64 +
                                      lane) * 8);
    }
    bf16x8 af[4];
#pragma unroll
    for (int mb = 0; mb < 4; ++mb)
      af[mb] = *(const bf16x8*)&Alds[cur][(mb * 16 + lc) * LDK + q * 8];
#pragma unroll
    for (int mb = 0; mb < 4; ++mb)
#pragma unroll
      for (int nb = 0; nb < 4; ++nb)
        acc[mb][nb] = __builtin_amdgcn_mfma_f32_16x16x32_bf16(
            af[mb], bfr[nb], acc[mb][nb], 0, 0, 0);
    if (kt < 15) cvtwr(pv, qv, cur ^ 1);
  }

  // epilogue: +eb2, LN over 512 cols, relu, masked seg-sum
  float bv[4], gv[4], bev[4];
#pragma unroll
  for (int nb = 0; nb < 4; ++nb) {
    int col = w * 64 + nb * 16 + lc;
    bv[nb] = b2[col];
    gv[nb] = g[col];
    bev[nb] = be[col];
  }
#pragma unroll
  for (int mb = 0; mb < 4; ++mb)
#pragma unroll
    for (int nb = 0; nb < 4; ++nb)
#pragma unroll
      for (int r = 0; r < 4; ++r) acc[mb][nb][r] += bv[nb];

#pragma unroll
  for (int mb = 0; mb < 4; ++mb) {
    float ps[4] = {0, 0, 0, 0}, pq2[4] = {0, 0, 0, 0};
#pragma unroll
    for (int nb = 0; nb < 4; ++nb)
#pragma unroll
      for (int r = 0; r < 4; ++r) {
        float x = acc[mb][nb][r];
        ps[r] += x;
        pq2[r] += x * x;
      }
#pragma unroll
    for (int d = 1; d < 16; d <<= 1)
#pragma unroll
      for (int r = 0; r < 4; ++r) {
        ps[r] += __shfl_xor(ps[r], d, 64);
        pq2[r] += __shfl_xor(pq2[r], d, 64);
      }
    if (lc == 0)
#pragma unroll
      for (int r = 0; r < 4; ++r) {
        int row = mb * 16 + q * 4 + r;
        s_sum[row * 8 + w] = ps[r];
        s_sq[row * 8 + w] = pq2[r];
      }
  }
  __syncthreads();
#pragma unroll
  for (int mb = 0; mb < 4; ++mb) {
    float sv[4] = {0, 0, 0, 0};
#pragma unroll
    for (int r = 0; r < 4; ++r) {
      int row = mb * 16 + q * 4 + r;
      float tot = 0.f, tsq = 0.f;
#pragma unroll
      for (int wv = 0; wv < 8; ++wv) {
        tot += s_sum[row * 8 + wv];
        tsq += s_sq[row * 8 + wv];
      }
      float m = tot * (1.f / 512.f);
      float rstd = rsqrtf(tsq * (1.f / 512.f) - m * m + 1e-5f);
#pragma unroll
      for (int nb = 0; nb < 4; ++nb) {
        float h = (acc[mb][nb][r] - m) * rstd * gv[nb] + bev[nb];
        h = fmaxf(h, 0.f);
        if (q * 4 + r != 15) sv[nb] += h;
      }
    }
#pragma unroll
    for (int nb = 0; nb < 4; ++nb) {
      sv[nb] += __shfl_xor(sv[nb], 16, 64);
      sv[nb] += __shfl_xor(sv[nb], 32, 64);
    }
    if (lane < 16)
#pragma unroll
      for (int nb = 0; nb < 4; ++nb)
        S[(size_t)(g0 + mb) * 512 + w * 64 + nb * 16 + lc] =
            __float2bfloat16(sv[nb]);
  }
}

// ---------------------------------------------------------------- gemm_ln_out
// n2 = relu(LN(A @ nW2t^T + nb2)) kept in LDS; out = n2 @ nW3 + nb3 -> d_out.
// tile 32 rows; 256 thr = 4 waves. Second GEMM: wave w covers out cols
// [w*32, w*32+32), B-frags from frag-layout nW3f (barrier-free loop).
__global__ __launch_bounds__(256) void gemm_ln_out(
    const bf16* __restrict__ A, const bf16* __restrict__ Bt,
    const float* __restrict__ bias, const float* __restrict__ g,
    const float* __restrict__ be, const bf16* __restrict__ Wf3,
    const float* __restrict__ nb3, float* __restrict__ Out) {
  __shared__ short Alds[32 * LDK];
  __shared__ short Blds[512 * LDK];  // overlay: n2 tile [32][LDN] after K-loop
  __shared__ float s_sum[32 * 4];
  __shared__ float s_sq[32 * 4];
  const int t = threadIdx.x;
  const int wid = t >> 6, lane = t & 63, q = lane >> 4, lc = lane & 15;
  const int m0 = blockIdx.x * 32;
  const f32x4 zz = {0.f, 0.f, 0.f, 0.f};
  f32x4 acc[2][8];
#pragma unroll
  for (int mb = 0; mb < 2; ++mb)
#pragma unroll
    for (int nb = 0; nb < 8; ++nb) acc[mb][nb] = zz;

  const int arr = t >> 3, akk = (t & 7) * 4;
  for (int k0 = 0; k0 < 512; k0 += 32) {
    uint2 va = *(const uint2*)(A + (size_t)(m0 + arr) * 512 + k0 + akk);
    *(uint2*)&Alds[arr * LDK + akk] = va;
#pragma unroll
    for (int i = 0; i < 2; ++i) {
      int n = t + i * 256;
#pragma unroll
      for (int s = 0; s < 4; ++s) {
        uint4 wv = *(const uint4*)(Bt + (size_t)n * 512 + k0 + s * 8);
        *(uint4*)&Blds[n * LDK + s * 8] = wv;
      }
    }
    __syncthreads();
    bf16x8 af[2], bfr[8];
#pragma unroll
    for (int mb = 0; mb < 2; ++mb)
      af[mb] = *(const bf16x8*)&Alds[(mb * 16 + lc) * LDK + q * 8];
#pragma unroll
    for (int nb = 0; nb < 8; ++nb)
      bfr[nb] = *(const bf16x8*)&Blds[(wid * 128 + nb * 16 + lc) * LDK + q * 8];
#pragma unroll
    for (int mb = 0; mb < 2; ++mb)
#pragma unroll
      for (int nb = 0; nb < 8; ++nb)
        acc[mb][nb] = __builtin_amdgcn_mfma_f32_16x16x32_bf16(
            af[mb], bfr[nb], acc[mb][nb], 0, 0, 0);
    __syncthreads();
  }
  float bv[8], gv[8], bev[8];
#pragma unroll
  for (int nb = 0; nb < 8; ++nb) {
    int col = wid * 128 + nb * 16 + lc;
    bv[nb] = bias[col];
    gv[nb] = g[col];
    bev[nb] = be[col];
  }
#pragma unroll
  for (int mb = 0; mb < 2; ++mb)
#pragma unroll
    for (int nb = 0; nb < 8; ++nb)
#pragma unroll
      for (int r = 0; r < 4; ++r) acc[mb][nb][r] += bv[nb];

#pragma unroll
  for (int mb = 0; mb < 2; ++mb) {
    float ps[4] = {0, 0, 0, 0}, pq2[4] = {0, 0, 0, 0};
#pragma unroll
    for (int nb = 0; nb < 8; ++nb)
#pragma unroll
      for (int r = 0; r < 4; ++r) {
        float x = acc[mb][nb][r];
        ps[r] += x;
        pq2[r] += x * x;
      }
#pragma unroll
    for (int d = 1; d < 16; d <<= 1)
#pragma unroll
      for (int r = 0; r < 4; ++r) {
        ps[r] += __shfl_xor(ps[r], d, 64);
        pq2[r] += __shfl_xor(pq2[r], d, 64);
      }
    if (lc == 0)
#pragma unroll
      for (int r = 0; r < 4; ++r) {
        int row = mb * 16 + q * 4 + r;
        s_sum[row * 4 + wid] = ps[r];
        s_sq[row * 4 + wid] = pq2[r];
      }
  }
  __syncthreads();
  // LN -> n2 into LDS overlay (Blds dead)
  short* n2s = Blds;
#pragma unroll
  for (int mb = 0; mb < 2; ++mb)
#pragma unroll
    for (int r = 0; r < 4; ++r) {
      int row = mb * 16 + q * 4 + r;
      float tot = 0.f, tsq = 0.f;
#pragma unroll
      for (int wv = 0; wv < 4; ++wv) {
        tot += s_sum[row * 4 + wv];
        tsq += s_sq[row * 4 + wv];
      }
      float m = tot * (1.f / 512.f);
      float rstd = rsqrtf(tsq * (1.f / 512.f) - m * m + 1e-5f);
#pragma unroll
      for (int nb = 0; nb < 8; ++nb) {
        int col = wid * 128 + nb * 16 + lc;
        float h = (acc[mb][nb][r] - m) * rstd * gv[nb] + bev[nb];
        n2s[row * LDN + col] = f2bf(fmaxf(h, 0.f));
      }
    }
  __syncthreads();
  // second GEMM: out[32 x 128] = n2 @ nW3 + nb3; wave w -> cols w*32..+32
  f32x4 acc2[2][2];
#pragma unroll
  for (int mb = 0; mb < 2; ++mb)
#pragma unroll
    for (int nb = 0; nb < 2; ++nb) acc2[mb][nb] = zz;
#pragma unroll 2
  for (int kt = 0; kt < 16; ++kt) {
    bf16x8 af2[2], bf2[2];
#pragma unroll
    for (int nb = 0; nb < 2; ++nb)
      bf2[nb] = *(const bf16x8*)(Wf3 +
                                 (((size_t)kt * 8 + wid * 2 + nb) * 64 + lane) * 8);
#pragma unroll
    for (int mb = 0; mb < 2; ++mb)
      af2[mb] = *(const bf16x8*)&n2s[(mb * 16 + lc) * LDN + kt * 32 + q * 8];
#pragma unroll
    for (int mb = 0; mb < 2; ++mb)
#pragma unroll
      for (int nb = 0; nb < 2; ++nb)
        acc2[mb][nb] = __builtin_amdgcn_mfma_f32_16x16x32_bf16(
            af2[mb], bf2[nb], acc2[mb][nb], 0, 0, 0);
  }
#pragma unroll
  for (int mb = 0; mb < 2; ++mb)
#pragma unroll
    for (int nb = 0; nb < 2; ++nb) {
      int col = wid * 32 + nb * 16 + lc;
      float b3 = nb3[col];
#pragma unroll
      for (int r = 0; r < 4; ++r) {
        int row = mb * 16 + q * 4 + r;
        Out[(size_t)(m0 + row) * 128 + col] = acc2[mb][nb][r] + b3;
      }
    }
}

// ---------------------------------------------------------------- launch
extern "C" void kernel_launch(void* const* d_in, const int* in_sizes, int n_in,
                              void* d_out, int out_size, void* d_ws,
                              size_t ws_size, hipStream_t stream) {
  const float* states = (const float*)d_in[0];
  const int* action = (const int*)d_in[1];
  const float* eW1 = (const float*)d_in[2];
  const float* eb1 = (const float*)d_in[3];
  const float* eW2 = (const float*)d_in[4];
  const float* eb2 = (const float*)d_in[5];
  const float* eg = (const float*)d_in[6];
  const float* ebt = (const float*)d_in[7];
  const float* eW3 = (const float*)d_in[8];
  const float* eb3 = (const float*)d_in[9];
  const float* nW1 = (const float*)d_in[10];
  const float* nb1 = (const float*)d_in[11];
  const float* nW2 = (const float*)d_in[12];
  const float* nb2 = (const float*)d_in[13];
  const float* ng = (const float*)d_in[14];
  const float* nbt = (const float*)d_in[15];
  const float* nW3 = (const float*)d_in[16];
  const float* nb3 = (const float*)d_in[17];

  const int BIG = 1 << 30;

  // ---- workspace (bf16 unless noted)
  char* w = (char*)d_ws;
  bf16* BtPQ = (bf16*)w;     w += (size_t)1024 * 128 * 2;
  bf16* eW2f = (bf16*)w;     w += (size_t)512 * 512 * 2;   // frag layout
  bf16* nW1t = (bf16*)w;     w += (size_t)512 * 648 * 2;   // k: 0..127 nodes, 136.. agg-part
  bf16* nW2t = (bf16*)w;     w += (size_t)512 * 512 * 2;
  bf16* nW3f = (bf16*)w;     w += (size_t)512 * 128 * 2;   // frag layout
  bf16* eW3b = (bf16*)w;     w += (size_t)512 * 512 * 2;   // raw bf16 copy of eW3
  bf16* Bt2 = (bf16*)w;      w += (size_t)512 * 512 * 2;   // (eW3@nW1_agg)^T-ish
  float* bfold = (float*)w;  w += (size_t)512 * 4;
  bf16* statesb = (bf16*)w;  w += (size_t)8192 * 128 * 2;
  bf16* PQ = (bf16*)w;       w += (size_t)8192 * 1024 * 2; // later: n1 (1st half)
  bf16* S = (bf16*)w;        w += (size_t)8192 * 512 * 2;
  bf16* n1 = PQ;

  cvt_f32_bf16<<<1024, 256, 0, stream>>>(states, (short*)statesb, 8192 * 128);
  cvt_f32_bf16<<<256, 256, 0, stream>>>(eW3, (short*)eW3b, 512 * 512);

  TJobs js;
  js.j[0] = {eW1,           (unsigned short*)BtPQ,             512, 128, 128, 512};
  js.j[1] = {eW1 + 128*512, (unsigned short*)(BtPQ + 512*128), 512, 128, 128, 512};
  js.j[2] = {nW1,           (unsigned short*)nW1t,             512, 648, 128, 512};
  js.j[3] = {nW1 + 132*512, (unsigned short*)(nW1t + 136),     512, 648, 512, 512};
  js.j[4] = {nW2,           (unsigned short*)nW2t,             512, 512, 512, 512};
  transpose_multi<<<dim3(16, 16, 5), 256, 0, stream>>>(js);
  prep_wfrag<<<1024, 256, 0, stream>>>(eW2, (short*)eW2f, 5, 512);
  prep_wfrag<<<256, 256, 0, stream>>>(nW3, (short*)nW3f, 3, 128);

  // Bt2[n][k] = sum_h nW1_agg^T[n][h] * eW3[k][h]  (== (eW3@nW1_agg) transposed)
  gemm_bt<false, false, false, false><<<dim3(4, 4), 256, 0, stream>>>(
      nW1t + 136, 512, 648, eW3b, 512, nullptr, 0, 0, nullptr, 0, nullptr, 0.f,
      0, nullptr, nullptr, Bt2, 512);
  fold_bias<<<1, 512, 0, stream>>>(nb1, eb3, nW1, bfold);

  // PQ = [nodes@eW1[:128]+eb1 | nodes@eW1[128:]]
  gemm_bt<false, false, false, false><<<dim3(8, 64), 256, 0, stream>>>(
      statesb, 128, 128, BtPQ, 128, nullptr, 0, 0, nullptr, 0, eb1, 1.f, 512,
      nullptr, nullptr, PQ, 1024);

  // fused edge layer-2 + LN + relu + segment-sum -> S
  edge_ln_seg4<<<2048, 512, 0, stream>>>(PQ, eW2f, eb2, eg, ebt, S);

  // n1 = relu(nodes@nW1[:128] + onehot + S@W_c + b_fold)   (n1 aliases PQ)
  gemm_bt<false, true, true, true><<<dim3(4, 64), 256, 0, stream>>>(
      statesb, 128, 128, nW1t, 648, S, 512, 512, Bt2, 512, bfold, 1.f, BIG,
      action, nW1 + 128 * 512, n1, 512);

  // out = relu(LN(n1@nW2+nb2)) @ nW3 + nb3  (fused, fp32 out)
  gemm_ln_out<<<256, 256, 0, stream>>>(n1, nW2t, nb2, ng, nbt, nW3f, nb3,
                                       (float*)d_out);

  (void)in_sizes; (void)n_in; (void)out_size; (void)ws_size;
}